// Round 1
// baseline (1164.873 us; speedup 1.0000x reference)
//
#include <hip/hip_runtime.h>
#include <math.h>

#define NGENES 19836
#define BATCH 8
#define DIN 11
#define DH 64
#define NNODES (BATCH * NGENES)        /* 158688 */
#define NEDGES (NNODES * 16)           /* 2539008 */
#define NDH (NNODES * DH)              /* 10156032 */

/* output layout (floats): preds[8], w[NNODES], sae_loss[1], dec[NNODES*64] */
#define OUT_PREDS 0
#define OUT_W 8
#define OUT_SAE (8 + NNODES)
#define OUT_DEC (9 + NNODES)

__device__ __forceinline__ float gelu_f(float x) {
    return 0.5f * x * (1.0f + erff(x * 0.70710678118654752f));
}

__device__ __forceinline__ float bcast(float v, int lane) {
    return __int_as_float(__builtin_amdgcn_readlane(__float_as_int(v), lane));
}

__device__ __forceinline__ float wave_sum(float v) {
    #pragma unroll
    for (int o = 32; o; o >>= 1) v += __shfl_xor(v, o, 64);
    return v;
}

/* K1: h = gelu(x @ enc_W.T + enc_b) + gene_emb[gene] */
__global__ void k_encoder(const float* __restrict__ x, const float* __restrict__ encW,
                          const float* __restrict__ encB, const float* __restrict__ gemb,
                          float* __restrict__ h) {
    int lane = threadIdx.x & 63;
    int wid = (blockIdx.x * blockDim.x + threadIdx.x) >> 6;
    int tw = (gridDim.x * blockDim.x) >> 6;
    int chunk = (NNODES + tw - 1) / tw;
    int start = wid * chunk;
    int end = min(start + chunk, NNODES);
    float wreg[DIN];
    #pragma unroll
    for (int k = 0; k < DIN; ++k) wreg[k] = encW[lane * DIN + k];
    float bias = encB[lane];
    for (int node = start; node < end; ++node) {
        const float* xr = x + (size_t)node * DIN;
        float acc = bias;
        #pragma unroll
        for (int k = 0; k < DIN; ++k) acc = fmaf(xr[k], wreg[k], acc);
        int gene = node % NGENES;
        h[(size_t)node * DH + lane] = gelu_f(acc) + gemb[(size_t)gene * DH + lane];
    }
}

/* K3: agg[dst] += h[src] (wave per edge, lane = feature) */
__global__ void k_edges(const int* __restrict__ src, const int* __restrict__ dst,
                        const float* __restrict__ h, float* __restrict__ agg) {
    int lane = threadIdx.x & 63;
    int wid = (blockIdx.x * blockDim.x + threadIdx.x) >> 6;
    int tw = (gridDim.x * blockDim.x) >> 6;
    int chunk = (NEDGES + tw - 1) / tw;
    int start = wid * chunk;
    int end = min(start + chunk, NEDGES);
    for (int e = start; e < end; ++e) {
        int s = src[e];
        int t = dst[e];
        float v = h[(size_t)s * DH + lane];
        atomicAdd(&agg[(size_t)t * DH + lane], v);
    }
}

/* K4: h2 = (h + agg) @ gin_W.T (in place into h), accumulate per-feature sum/sumsq */
__global__ void k_gin(const float* __restrict__ ginW, float* __restrict__ h,
                      const float* __restrict__ agg, float* __restrict__ stats) {
    int lane = threadIdx.x & 63;
    int wid = (blockIdx.x * blockDim.x + threadIdx.x) >> 6;
    int tw = (gridDim.x * blockDim.x) >> 6;
    int chunk = (NNODES + tw - 1) / tw;
    int start = wid * chunk;
    int end = min(start + chunk, NNODES);
    float wr[DH];
    #pragma unroll
    for (int k = 0; k < DH; ++k) wr[k] = ginW[lane * DH + k];
    float s1 = 0.f, s2 = 0.f;
    for (int node = start; node < end; ++node) {
        float t = h[(size_t)node * DH + lane] + agg[(size_t)node * DH + lane];
        float a0 = 0.f, a1 = 0.f;
        #pragma unroll
        for (int k = 0; k < DH; k += 2) {
            a0 = fmaf(wr[k], bcast(t, k), a0);
            a1 = fmaf(wr[k + 1], bcast(t, k + 1), a1);
        }
        float outv = a0 + a1;
        h[(size_t)node * DH + lane] = outv;
        s1 += outv;
        s2 += outv * outv;
    }
    __shared__ float red[2][256];
    red[0][threadIdx.x] = s1;
    red[1][threadIdx.x] = s2;
    __syncthreads();
    if (threadIdx.x < 64) {
        float t1 = red[0][threadIdx.x] + red[0][threadIdx.x + 64] + red[0][threadIdx.x + 128] + red[0][threadIdx.x + 192];
        float t2 = red[1][threadIdx.x] + red[1][threadIdx.x + 64] + red[1][threadIdx.x + 128] + red[1][threadIdx.x + 192];
        atomicAdd(&stats[threadIdx.x], t1);
        atomicAdd(&stats[64 + threadIdx.x], t2);
    }
}

/* K5: bn scale/shift from stats */
__global__ void k_bnparams(const float* __restrict__ stats, const float* __restrict__ bnw,
                           const float* __restrict__ bnb, float* __restrict__ bnp) {
    int d = threadIdx.x;
    float inv_n = 1.0f / (float)NNODES;
    float mu = stats[d] * inv_n;
    float var = stats[64 + d] * inv_n - mu * mu;
    float sc = bnw[d] * rsqrtf(var + 1e-5f);
    bnp[d] = sc;
    bnp[64 + d] = bnb[d] - mu * sc;
}

/* K6a: h3 = gelu(bn(h2)); keys = h3@keyW.T+kb; wq = sigmoid(keys.qw); z = (h3@valW.T+vb)*wq */
__global__ void k_attn(const float* __restrict__ h, const float* __restrict__ bnp,
                       const float* __restrict__ keyW, const float* __restrict__ keyB,
                       const float* __restrict__ qw, const float* __restrict__ valW,
                       const float* __restrict__ valB, float* __restrict__ zbuf,
                       float* __restrict__ wout) {
    int lane = threadIdx.x & 63;
    int wid = (blockIdx.x * blockDim.x + threadIdx.x) >> 6;
    int tw = (gridDim.x * blockDim.x) >> 6;
    int chunk = (NNODES + tw - 1) / tw;
    int start = wid * chunk;
    int end = min(start + chunk, NNODES);
    float kw[DH], vw[DH];
    #pragma unroll
    for (int k = 0; k < DH; ++k) {
        kw[k] = keyW[lane * DH + k];
        vw[k] = valW[lane * DH + k];
    }
    float kb = keyB[lane], vb = valB[lane], qv = qw[lane];
    float sc = bnp[lane], sh = bnp[64 + lane];
    for (int node = start; node < end; ++node) {
        float h2 = h[(size_t)node * DH + lane];
        float h3 = gelu_f(fmaf(h2, sc, sh));
        float ka0 = 0.f, ka1 = 0.f, va0 = 0.f, va1 = 0.f;
        #pragma unroll
        for (int k = 0; k < DH; k += 2) {
            float b0 = bcast(h3, k);
            float b1 = bcast(h3, k + 1);
            ka0 = fmaf(kw[k], b0, ka0);
            va0 = fmaf(vw[k], b0, va0);
            ka1 = fmaf(kw[k + 1], b1, ka1);
            va1 = fmaf(vw[k + 1], b1, va1);
        }
        float keys = ka0 + ka1 + kb;
        float p = wave_sum(keys * qv);
        float wq = 1.0f / (1.0f + expf(-p));
        float z = (va0 + va1 + vb) * wq;
        zbuf[(size_t)node * DH + lane] = z;
        if (lane == 0) wout[node] = wq;
    }
}

/* K6b: enc = relu(z@encW.T+eb); dec = enc@decW.T+db; loss partials; g_h += dec*wq */
__global__ void k_sae(const float* __restrict__ zbuf, const float* __restrict__ encW,
                      const float* __restrict__ encB, const float* __restrict__ decW,
                      const float* __restrict__ decB, const float* __restrict__ wout,
                      float* __restrict__ decout, float* __restrict__ g_h,
                      float* __restrict__ loss) {
    int lane = threadIdx.x & 63;
    int wid = (blockIdx.x * blockDim.x + threadIdx.x) >> 6;
    int tw = (gridDim.x * blockDim.x) >> 6;
    int chunk = (NNODES + tw - 1) / tw;
    int start = wid * chunk;
    int end = min(start + chunk, NNODES);
    float ew[DH], dw[DH];
    #pragma unroll
    for (int k = 0; k < DH; ++k) {
        ew[k] = encW[lane * DH + k];
        dw[k] = decW[lane * DH + k];
    }
    float eb = encB[lane], db = decB[lane];
    float sq = 0.f, l1 = 0.f, gacc = 0.f;
    int cur_g = (start < NNODES) ? (start / NGENES) : 0;
    for (int node = start; node < end; ++node) {
        float z = zbuf[(size_t)node * DH + lane];
        float ea0 = 0.f, ea1 = 0.f;
        #pragma unroll
        for (int k = 0; k < DH; k += 2) {
            ea0 = fmaf(ew[k], bcast(z, k), ea0);
            ea1 = fmaf(ew[k + 1], bcast(z, k + 1), ea1);
        }
        float enc = fmaxf(ea0 + ea1 + eb, 0.0f);
        float da0 = 0.f, da1 = 0.f;
        #pragma unroll
        for (int k = 0; k < DH; k += 2) {
            da0 = fmaf(dw[k], bcast(enc, k), da0);
            da1 = fmaf(dw[k + 1], bcast(enc, k + 1), da1);
        }
        float dec = da0 + da1 + db;
        float wq = wout[node];
        decout[(size_t)node * DH + lane] = dec;
        float diff = dec - z;
        sq = fmaf(diff, diff, sq);
        l1 += fabsf(enc);
        int g = node / NGENES;
        if (g != cur_g) {
            atomicAdd(&g_h[cur_g * DH + lane], gacc);
            gacc = 0.f;
            cur_g = g;
        }
        gacc = fmaf(dec, wq, gacc);
    }
    if (start < end) atomicAdd(&g_h[cur_g * DH + lane], gacc);
    sq = wave_sum(sq);
    l1 = wave_sum(l1);
    if (lane == 0) {
        atomicAdd(&loss[0], sq);
        atomicAdd(&loss[1], l1);
    }
}

/* K7: preds = gelu(g_h@W1.T+b1)@W2.T + b2; sae_loss final */
__global__ void k_pred(const float* __restrict__ g_h, const float* __restrict__ W1,
                       const float* __restrict__ b1, const float* __restrict__ W2,
                       const float* __restrict__ b2, const float* __restrict__ loss,
                       float* __restrict__ out) {
    int lane = threadIdx.x;
    float w1[DH];
    #pragma unroll
    for (int k = 0; k < DH; ++k) w1[k] = W1[lane * DH + k];
    float bb = b1[lane], w2 = W2[lane];
    for (int g = 0; g < BATCH; ++g) {
        float gh = g_h[g * DH + lane];
        float a0 = 0.f, a1 = 0.f;
        #pragma unroll
        for (int k = 0; k < DH; k += 2) {
            a0 = fmaf(w1[k], bcast(gh, k), a0);
            a1 = fmaf(w1[k + 1], bcast(gh, k + 1), a1);
        }
        float t = gelu_f(a0 + a1 + bb);
        float p = wave_sum(t * w2);
        if (lane == 0) out[OUT_PREDS + g] = p + b2[0];
    }
    if (lane == 0) out[OUT_SAE] = (loss[0] + loss[1]) * (1.0f / ((float)NNODES * (float)DH));
}

extern "C" void kernel_launch(void* const* d_in, const int* in_sizes, int n_in,
                              void* d_out, int out_size, void* d_ws, size_t ws_size,
                              hipStream_t stream) {
    const float* x    = (const float*)d_in[0];
    const int* src    = (const int*)d_in[1];
    const int* dst    = (const int*)d_in[2];
    const float* encW = (const float*)d_in[3];
    const float* encB = (const float*)d_in[4];
    const float* gemb = (const float*)d_in[5];
    const float* ginW = (const float*)d_in[6];
    const float* bnw  = (const float*)d_in[7];
    const float* bnb  = (const float*)d_in[8];
    const float* keyW = (const float*)d_in[9];
    const float* keyB = (const float*)d_in[10];
    const float* qw   = (const float*)d_in[11];
    const float* valW = (const float*)d_in[12];
    const float* valB = (const float*)d_in[13];
    const float* saeEncW = (const float*)d_in[14];
    const float* saeEncB = (const float*)d_in[15];
    const float* saeDecW = (const float*)d_in[16];
    const float* saeDecB = (const float*)d_in[17];
    const float* pW1  = (const float*)d_in[18];
    const float* pb1  = (const float*)d_in[19];
    const float* pW2  = (const float*)d_in[20];
    const float* pb2  = (const float*)d_in[21];

    float* out = (float*)d_out;
    float* ws = (float*)d_ws;

    float* agg   = ws;                      /* NDH floats; later reused as zbuf */
    float* stats = ws + NDH;                /* 128 */
    float* g_h   = ws + NDH + 128;          /* 512 */
    float* loss  = ws + NDH + 640;          /* 2 */
    float* bnp   = ws + NDH + 642;          /* 128 */
    float* zbuf  = agg;

    float* h    = out + OUT_DEC;            /* h / h2 lives in the dec output region */
    float* wout = out + OUT_W;

    /* zero agg + stats + g_h + loss (+bnp slack) */
    hipMemsetAsync(d_ws, 0, (size_t)(NDH + 770) * sizeof(float), stream);

    k_encoder<<<2048, 256, 0, stream>>>(x, encW, encB, gemb, h);
    k_edges<<<4096, 256, 0, stream>>>(src, dst, h, agg);
    k_gin<<<1024, 256, 0, stream>>>(ginW, h, agg, stats);
    k_bnparams<<<1, 64, 0, stream>>>(stats, bnw, bnb, bnp);
    k_attn<<<1024, 256, 0, stream>>>(h, bnp, keyW, keyB, qw, valW, valB, zbuf, wout);
    k_sae<<<1024, 256, 0, stream>>>(zbuf, saeEncW, saeEncB, saeDecW, saeDecB, wout, h, g_h, loss);
    k_pred<<<1, 64, 0, stream>>>(g_h, pW1, pb1, pW2, pb2, loss, out);
}

// Round 2
// 985.398 us; speedup vs baseline: 1.1821x; 1.1821x over previous
//
#include <hip/hip_runtime.h>
#include <math.h>

#define NGENES 19836
#define BATCH 8
#define DIN 11
#define DH 64
#define NNODES (BATCH * NGENES)        /* 158688 */
#define NEDGES (NNODES * 16)           /* 2539008 */
#define NDH (NNODES * DH)              /* 10156032 */

#define SCAN_CHUNK 1024
#define NSBLK ((NNODES + SCAN_CHUNK - 1) / SCAN_CHUNK)  /* 155 */

/* output layout (floats): preds[8], w[NNODES], sae_loss[1], dec[NNODES*64] */
#define OUT_PREDS 0
#define OUT_W 8
#define OUT_SAE (8 + NNODES)
#define OUT_DEC (9 + NNODES)

__device__ __forceinline__ float gelu_f(float x) {
    return 0.5f * x * (1.0f + erff(x * 0.70710678118654752f));
}

__device__ __forceinline__ float bcast(float v, int lane) {
    return __int_as_float(__builtin_amdgcn_readlane(__float_as_int(v), lane));
}

__device__ __forceinline__ float wave_sum(float v) {
    #pragma unroll
    for (int o = 32; o; o >>= 1) v += __shfl_xor(v, o, 64);
    return v;
}

/* K1: h = gelu(x @ enc_W.T + enc_b) + gene_emb[gene] */
__global__ void k_encoder(const float* __restrict__ x, const float* __restrict__ encW,
                          const float* __restrict__ encB, const float* __restrict__ gemb,
                          float* __restrict__ h) {
    int lane = threadIdx.x & 63;
    int wid = (blockIdx.x * blockDim.x + threadIdx.x) >> 6;
    int tw = (gridDim.x * blockDim.x) >> 6;
    int chunk = (NNODES + tw - 1) / tw;
    int start = wid * chunk;
    int end = min(start + chunk, NNODES);
    float wreg[DIN];
    #pragma unroll
    for (int k = 0; k < DIN; ++k) wreg[k] = encW[lane * DIN + k];
    float bias = encB[lane];
    for (int node = start; node < end; ++node) {
        const float* xr = x + (size_t)node * DIN;
        float acc = bias;
        #pragma unroll
        for (int k = 0; k < DIN; ++k) acc = fmaf(xr[k], wreg[k], acc);
        int gene = node % NGENES;
        h[(size_t)node * DH + lane] = gelu_f(acc) + gemb[(size_t)gene * DH + lane];
    }
}

/* CSR build: histogram of dst */
__global__ void k_hist(const int* __restrict__ dst, int* __restrict__ counts) {
    int i = blockIdx.x * blockDim.x + threadIdx.x;
    int stride = gridDim.x * blockDim.x;
    for (int e = i; e < NEDGES; e += stride)
        atomicAdd(&counts[dst[e]], 1);
}

/* scan pass 1: per-block sums (block covers SCAN_CHUNK counts) */
__global__ void k_scan1(const int* __restrict__ counts, int* __restrict__ bsum) {
    __shared__ int red[256];
    int base = blockIdx.x * SCAN_CHUNK + threadIdx.x * 4;
    int s = 0;
    #pragma unroll
    for (int i = 0; i < 4; ++i) {
        int n = base + i;
        if (n < NNODES) s += counts[n];
    }
    red[threadIdx.x] = s;
    __syncthreads();
    for (int o = 128; o; o >>= 1) {
        if (threadIdx.x < o) red[threadIdx.x] += red[threadIdx.x + o];
        __syncthreads();
    }
    if (threadIdx.x == 0) bsum[blockIdx.x] = red[0];
}

/* scan pass 2: exclusive scan of 155 block sums (tiny, serial) */
__global__ void k_scan2(const int* __restrict__ bsum, int* __restrict__ boff) {
    if (threadIdx.x == 0) {
        int acc = 0;
        for (int i = 0; i < NSBLK; ++i) { boff[i] = acc; acc += bsum[i]; }
    }
}

/* scan pass 3: intra-block exclusive scan -> offsets, cursor */
__global__ void k_scan3(const int* __restrict__ counts, const int* __restrict__ boff,
                        int* __restrict__ offsets, int* __restrict__ cursor) {
    __shared__ int red[256];
    int t = threadIdx.x;
    int base = blockIdx.x * SCAN_CHUNK + t * 4;
    int c[4];
    int s = 0;
    #pragma unroll
    for (int i = 0; i < 4; ++i) {
        int n = base + i;
        c[i] = (n < NNODES) ? counts[n] : 0;
        s += c[i];
    }
    red[t] = s;
    __syncthreads();
    for (int o = 1; o < 256; o <<= 1) {
        int v = (t >= o) ? red[t - o] : 0;
        __syncthreads();
        red[t] += v;
        __syncthreads();
    }
    int excl = red[t] - s + boff[blockIdx.x];
    #pragma unroll
    for (int i = 0; i < 4; ++i) {
        int n = base + i;
        if (n < NNODES) { offsets[n] = excl; cursor[n] = excl; }
        excl += c[i];
    }
}

/* scatter edges into CSR; store LOCAL src id (src and dst share a graph) */
__global__ void k_scatter(const int* __restrict__ src, const int* __restrict__ dst,
                          int* __restrict__ cursor, unsigned short* __restrict__ csr) {
    int i = blockIdx.x * blockDim.x + threadIdx.x;
    int stride = gridDim.x * blockDim.x;
    for (int e = i; e < NEDGES; e += stride) {
        int p = atomicAdd(&cursor[dst[e]], 1);
        csr[p] = (unsigned short)(src[e] % NGENES);
    }
}

/* fused: agg gather + GIN matmul + BN stats. wave per node, strided for L2 locality */
__global__ void k_aggin(const float* __restrict__ h, const int* __restrict__ offsets,
                        const int* __restrict__ counts, const unsigned short* __restrict__ csr,
                        const float* __restrict__ ginW, float* __restrict__ h2,
                        float* __restrict__ stats) {
    int lane = threadIdx.x & 63;
    int wid = (blockIdx.x * blockDim.x + threadIdx.x) >> 6;
    int tw = (gridDim.x * blockDim.x) >> 6;
    float wr[DH];
    #pragma unroll
    for (int k = 0; k < DH; ++k) wr[k] = ginW[lane * DH + k];
    float s1 = 0.f, s2 = 0.f;
    for (int node = wid; node < NNODES; node += tw) {
        int gbase = (node / NGENES) * NGENES;
        float a0 = h[(size_t)node * DH + lane], a1 = 0.f, a2 = 0.f, a3 = 0.f;
        int start = offsets[node];
        int cnt = counts[node];
        for (int e0 = 0; e0 < cnt; e0 += 64) {
            int nn = min(64, cnt - e0);
            int iv = (lane < nn) ? (int)csr[start + e0 + lane] : 0;
            int j = 0;
            for (; j + 3 < nn; j += 4) {
                int v0 = gbase + __shfl(iv, j, 64);
                int v1 = gbase + __shfl(iv, j + 1, 64);
                int v2 = gbase + __shfl(iv, j + 2, 64);
                int v3 = gbase + __shfl(iv, j + 3, 64);
                a0 += h[(size_t)v0 * DH + lane];
                a1 += h[(size_t)v1 * DH + lane];
                a2 += h[(size_t)v2 * DH + lane];
                a3 += h[(size_t)v3 * DH + lane];
            }
            for (; j < nn; ++j)
                a0 += h[(size_t)(gbase + __shfl(iv, j, 64)) * DH + lane];
        }
        float tval = (a0 + a1) + (a2 + a3);
        float m0 = 0.f, m1 = 0.f;
        #pragma unroll
        for (int k = 0; k < DH; k += 2) {
            m0 = fmaf(wr[k], bcast(tval, k), m0);
            m1 = fmaf(wr[k + 1], bcast(tval, k + 1), m1);
        }
        float outv = m0 + m1;
        h2[(size_t)node * DH + lane] = outv;
        s1 += outv;
        s2 += outv * outv;
    }
    __shared__ float red[2][256];
    red[0][threadIdx.x] = s1;
    red[1][threadIdx.x] = s2;
    __syncthreads();
    if (threadIdx.x < 64) {
        float t1 = red[0][threadIdx.x] + red[0][threadIdx.x + 64] + red[0][threadIdx.x + 128] + red[0][threadIdx.x + 192];
        float t2 = red[1][threadIdx.x] + red[1][threadIdx.x + 64] + red[1][threadIdx.x + 128] + red[1][threadIdx.x + 192];
        atomicAdd(&stats[threadIdx.x], t1);
        atomicAdd(&stats[64 + threadIdx.x], t2);
    }
}

/* bn scale/shift from stats */
__global__ void k_bnparams(const float* __restrict__ stats, const float* __restrict__ bnw,
                           const float* __restrict__ bnb, float* __restrict__ bnp) {
    int d = threadIdx.x;
    float inv_n = 1.0f / (float)NNODES;
    float mu = stats[d] * inv_n;
    float var = stats[64 + d] * inv_n - mu * mu;
    float sc = bnw[d] * rsqrtf(var + 1e-5f);
    bnp[d] = sc;
    bnp[64 + d] = bnb[d] - mu * sc;
}

/* h3 = gelu(bn(h2)); keys/query sigmoid; z = (h3@valW.T+vb)*wq  (z in-place over h2) */
__global__ void k_attn(float* __restrict__ h2, const float* __restrict__ bnp,
                       const float* __restrict__ keyW, const float* __restrict__ keyB,
                       const float* __restrict__ qw, const float* __restrict__ valW,
                       const float* __restrict__ valB, float* __restrict__ wout) {
    int lane = threadIdx.x & 63;
    int wid = (blockIdx.x * blockDim.x + threadIdx.x) >> 6;
    int tw = (gridDim.x * blockDim.x) >> 6;
    int chunk = (NNODES + tw - 1) / tw;
    int start = wid * chunk;
    int end = min(start + chunk, NNODES);
    float kw[DH], vw[DH];
    #pragma unroll
    for (int k = 0; k < DH; ++k) {
        kw[k] = keyW[lane * DH + k];
        vw[k] = valW[lane * DH + k];
    }
    float kb = keyB[lane], vb = valB[lane], qv = qw[lane];
    float sc = bnp[lane], sh = bnp[64 + lane];
    for (int node = start; node < end; ++node) {
        float hv = h2[(size_t)node * DH + lane];
        float h3 = gelu_f(fmaf(hv, sc, sh));
        float ka0 = 0.f, ka1 = 0.f, va0 = 0.f, va1 = 0.f;
        #pragma unroll
        for (int k = 0; k < DH; k += 2) {
            float b0 = bcast(h3, k);
            float b1 = bcast(h3, k + 1);
            ka0 = fmaf(kw[k], b0, ka0);
            va0 = fmaf(vw[k], b0, va0);
            ka1 = fmaf(kw[k + 1], b1, ka1);
            va1 = fmaf(vw[k + 1], b1, va1);
        }
        float keys = ka0 + ka1 + kb;
        float p = wave_sum(keys * qv);
        float wq = 1.0f / (1.0f + expf(-p));
        float z = (va0 + va1 + vb) * wq;
        h2[(size_t)node * DH + lane] = z;
        if (lane == 0) wout[node] = wq;
    }
}

/* enc = relu(z@encW.T+eb); dec = enc@decW.T+db; loss partials; g_h += dec*wq */
__global__ void k_sae(const float* __restrict__ zbuf, const float* __restrict__ encW,
                      const float* __restrict__ encB, const float* __restrict__ decW,
                      const float* __restrict__ decB, const float* __restrict__ wout,
                      float* __restrict__ decout, float* __restrict__ g_h,
                      float* __restrict__ loss) {
    int lane = threadIdx.x & 63;
    int wid = (blockIdx.x * blockDim.x + threadIdx.x) >> 6;
    int tw = (gridDim.x * blockDim.x) >> 6;
    int chunk = (NNODES + tw - 1) / tw;
    int start = wid * chunk;
    int end = min(start + chunk, NNODES);
    float ew[DH], dw[DH];
    #pragma unroll
    for (int k = 0; k < DH; ++k) {
        ew[k] = encW[lane * DH + k];
        dw[k] = decW[lane * DH + k];
    }
    float eb = encB[lane], db = decB[lane];
    float sq = 0.f, l1 = 0.f, gacc = 0.f;
    int cur_g = (start < NNODES) ? (start / NGENES) : 0;
    for (int node = start; node < end; ++node) {
        float z = zbuf[(size_t)node * DH + lane];
        float ea0 = 0.f, ea1 = 0.f;
        #pragma unroll
        for (int k = 0; k < DH; k += 2) {
            ea0 = fmaf(ew[k], bcast(z, k), ea0);
            ea1 = fmaf(ew[k + 1], bcast(z, k + 1), ea1);
        }
        float enc = fmaxf(ea0 + ea1 + eb, 0.0f);
        float da0 = 0.f, da1 = 0.f;
        #pragma unroll
        for (int k = 0; k < DH; k += 2) {
            da0 = fmaf(dw[k], bcast(enc, k), da0);
            da1 = fmaf(dw[k + 1], bcast(enc, k + 1), da1);
        }
        float dec = da0 + da1 + db;
        float wq = wout[node];
        decout[(size_t)node * DH + lane] = dec;
        float diff = dec - z;
        sq = fmaf(diff, diff, sq);
        l1 += fabsf(enc);
        int g = node / NGENES;
        if (g != cur_g) {
            atomicAdd(&g_h[cur_g * DH + lane], gacc);
            gacc = 0.f;
            cur_g = g;
        }
        gacc = fmaf(dec, wq, gacc);
    }
    if (start < end) atomicAdd(&g_h[cur_g * DH + lane], gacc);
    sq = wave_sum(sq);
    l1 = wave_sum(l1);
    if (lane == 0) {
        atomicAdd(&loss[0], sq);
        atomicAdd(&loss[1], l1);
    }
}

/* preds = gelu(g_h@W1.T+b1)@W2.T + b2; sae_loss final */
__global__ void k_pred(const float* __restrict__ g_h, const float* __restrict__ W1,
                       const float* __restrict__ b1, const float* __restrict__ W2,
                       const float* __restrict__ b2, const float* __restrict__ loss,
                       float* __restrict__ out) {
    int lane = threadIdx.x;
    float w1[DH];
    #pragma unroll
    for (int k = 0; k < DH; ++k) w1[k] = W1[lane * DH + k];
    float bb = b1[lane], w2 = W2[lane];
    for (int g = 0; g < BATCH; ++g) {
        float gh = g_h[g * DH + lane];
        float a0 = 0.f, a1 = 0.f;
        #pragma unroll
        for (int k = 0; k < DH; k += 2) {
            a0 = fmaf(w1[k], bcast(gh, k), a0);
            a1 = fmaf(w1[k + 1], bcast(gh, k + 1), a1);
        }
        float t = gelu_f(a0 + a1 + bb);
        float p = wave_sum(t * w2);
        if (lane == 0) out[OUT_PREDS + g] = p + b2[0];
    }
    if (lane == 0) out[OUT_SAE] = (loss[0] + loss[1]) * (1.0f / ((float)NNODES * (float)DH));
}

extern "C" void kernel_launch(void* const* d_in, const int* in_sizes, int n_in,
                              void* d_out, int out_size, void* d_ws, size_t ws_size,
                              hipStream_t stream) {
    const float* x    = (const float*)d_in[0];
    const int* src    = (const int*)d_in[1];
    const int* dst    = (const int*)d_in[2];
    const float* encW = (const float*)d_in[3];
    const float* encB = (const float*)d_in[4];
    const float* gemb = (const float*)d_in[5];
    const float* ginW = (const float*)d_in[6];
    const float* bnw  = (const float*)d_in[7];
    const float* bnb  = (const float*)d_in[8];
    const float* keyW = (const float*)d_in[9];
    const float* keyB = (const float*)d_in[10];
    const float* qw   = (const float*)d_in[11];
    const float* valW = (const float*)d_in[12];
    const float* valB = (const float*)d_in[13];
    const float* saeEncW = (const float*)d_in[14];
    const float* saeEncB = (const float*)d_in[15];
    const float* saeDecW = (const float*)d_in[16];
    const float* saeDecB = (const float*)d_in[17];
    const float* pW1  = (const float*)d_in[18];
    const float* pb1  = (const float*)d_in[19];
    const float* pW2  = (const float*)d_in[20];
    const float* pb2  = (const float*)d_in[21];

    float* out = (float*)d_out;
    float* ws = (float*)d_ws;

    /* ws layout */
    int*   counts  = (int*)ws;                     /* NNODES */
    float* stats   = ws + NNODES;                  /* 128 */
    float* g_h     = stats + 128;                  /* 512 */
    float* loss    = g_h + 512;                    /* 2 */
    float* bnp     = loss + 2;                     /* 128 */
    int*   offsets = (int*)(bnp + 128);            /* NNODES */
    int*   cursor  = offsets + NNODES;             /* NNODES */
    unsigned short* csr = (unsigned short*)(cursor + NNODES); /* NEDGES u16 */
    int*   bsum    = (int*)(csr + NEDGES);         /* 256 */
    int*   boff    = bsum + 256;                   /* 256 */
    float* h2      = (float*)(boff + 256);         /* NDH */

    float* h    = out + OUT_DEC;   /* encoder output lives in dec region until k_sae */
    float* wout = out + OUT_W;

    /* zero counts + stats/g_h/loss/bnp */
    hipMemsetAsync(d_ws, 0, (size_t)(NNODES + 770) * sizeof(float), stream);

    k_encoder<<<2048, 256, 0, stream>>>(x, encW, encB, gemb, h);
    k_hist<<<4096, 256, 0, stream>>>(dst, counts);
    k_scan1<<<NSBLK, 256, 0, stream>>>(counts, bsum);
    k_scan2<<<1, 64, 0, stream>>>(bsum, boff);
    k_scan3<<<NSBLK, 256, 0, stream>>>(counts, boff, offsets, cursor);
    k_scatter<<<4096, 256, 0, stream>>>(src, dst, cursor, csr);
    k_aggin<<<2048, 256, 0, stream>>>(h, offsets, counts, csr, ginW, h2, stats);
    k_bnparams<<<1, 64, 0, stream>>>(stats, bnw, bnb, bnp);
    k_attn<<<1024, 256, 0, stream>>>(h2, bnp, keyW, keyB, qw, valW, valB, wout);
    k_sae<<<1024, 256, 0, stream>>>(h2, saeEncW, saeEncB, saeDecW, saeDecB, wout, h, g_h, loss);
    k_pred<<<1, 64, 0, stream>>>(g_h, pW1, pb1, pW2, pb2, loss, out);
}